// Round 8
// baseline (555.081 us; speedup 1.0000x reference)
//
#include <hip/hip_runtime.h>
#include <math.h>

// VIN forward on MI355X — 2 WGs per image (row split) + per-iter mailbox sync.
// Sizes: N=128, H=W=64, CH_I=2, CH_H=150, CH_Q=10, N_ACT=8, VInum=36.
//
// R7 -> R8 changes:
//  * STOP fighting the remat: R5/R6/R7 all proved the allocator refolds any
//    register-hoisted copy of the 90 w_sw weights back into per-use LDS reads
//    (VGPR stuck at 116). Instead make the per-iteration reads cheap:
//    float4-padded layout swv4[9][3] -> 27 ds_read_b128 per thread-iter
//    (was 90 ds_read_b32), loaded per-d-slice with short liveness.
//  * Engage all 256 CUs: 256 WGs = (image b, half h), 32 rows each,
//    4 px/thread. Per-iteration halo = ONE 64-float row exchanged through a
//    d_ws mailbox: parity double-buffered slots + monotonic flags with
//    __hip_atomic acquire/release at AGENT scope (skew <= 1 iter => 2 slots
//    suffice; 256 WGs x 8 waves x <=82KB LDS are all co-resident => spin-safe).
//  * init_flags pre-kernel zeroes the 256 flags (d_ws is 0xAA-poisoned).
//  * LDS padded > 80 KB so 2 WGs can't pack on one CU (keeps 1 WG/CU spread).

#define XROW 69
#define VROW 67
#define VLROWS 34
#define VLSTR (VLROWS * VROW)      // 2278 floats per local v buffer

#define FLAG_OFF 32768             // float offset of flags[] in d_ws (128 KB of slots)

__global__ void init_flags(int* flags) { flags[threadIdx.x] = 0; }

__global__ void
__attribute__((amdgpu_flat_work_group_size(512, 512)))
__attribute__((amdgpu_waves_per_eu(2, 2)))
vin_kernel(const float* __restrict__ x,
           const int* __restrict__ S1,
           const int* __restrict__ S2,
           const int* __restrict__ VInum,
           const float* __restrict__ w0,
           const float* __restrict__ b0,
           const float* __restrict__ w_r,
           const float* __restrict__ w_q,
           const float* __restrict__ w_sw,
           const float* __restrict__ w_sw2,
           const float* __restrict__ w_dense,
           float* __restrict__ wsf,          // d_ws as float*
           float* __restrict__ out) {
    const int b = blockIdx.x & 127;          // image
    const int h = blockIdx.x >> 7;           // half: 0 = rows 0..31, 1 = rows 32..63
    const int t = threadIdx.x;
    const int r0 = h << 5;
    const int me = b * 2 + h, partner = b * 2 + (1 - h);
    int* flags = (int*)wsf + FLAG_OFF;

    __shared__ float xs0[68 * XROW];     // x ch0, [y+2][x+2], 2-halo of zeros
    __shared__ float xs1[68 * XROW];     // x ch1
    __shared__ float rs[66 * VROW];      // full-image r with 1-halo of zeros
    __shared__ float vloc[2 * VLSTR];    // v double buffer: rows r0-1..r0+32 (+halo)
    __shared__ float wtmp[840];
    __shared__ float wfin[60];
    __shared__ float4 swv4[27];          // w_sw v-part, [d][a-quad], a padded 10->12
    __shared__ float qsel[10];
    __shared__ float pad[1200];          // force LDS > 80KB => 1 WG/CU

    const int K = VInum[0];
    if (K == -123456789) { pad[t] = 1.f; rs[0] = pad[t & 1023]; }  // keep pad alive

    // ---- zero LDS (halos must be 0) ----
    for (int i = t; i < 68 * XROW; i += 512) { xs0[i] = 0.f; xs1[i] = 0.f; }
    for (int i = t; i < 66 * VROW; i += 512) rs[i] = 0.f;
    for (int i = t; i < 2 * VLSTR; i += 512) vloc[i] = 0.f;
    if (t < 27) {
        int d = t / 3, k = t % 3;
        float4 w;
        w.x = w_sw[d * 20 + 10 + 4 * k + 0];
        w.y = w_sw[d * 20 + 10 + 4 * k + 1];
        w.z = (4 * k + 2 < 10) ? w_sw[d * 20 + 10 + 4 * k + 2] : 0.f;
        w.w = (4 * k + 3 < 10) ? w_sw[d * 20 + 10 + 4 * k + 3] : 0.f;
        swv4[t] = w;
    }
    __syncthreads();

    // ================= PROLOGUE (full image per WG, as R5) =================
    const int rowP = t >> 3;          // 0..63
    const int cbP  = (t & 7) << 3;    // 0,8,...,56

    {
        const float* xb = x + (size_t)b * 64 * 64 * 2;
        const float4* xp = (const float4*)(xb + (rowP * 64 + cbP) * 2);
        #pragma unroll
        for (int g = 0; g < 4; ++g) {
            float4 v4 = xp[g];
            int px = cbP + g * 2;
            xs0[(rowP + 2) * XROW + px + 2] = v4.x;
            xs1[(rowP + 2) * XROW + px + 2] = v4.y;
            xs0[(rowP + 2) * XROW + px + 3] = v4.z;
            xs1[(rowP + 2) * XROW + px + 3] = v4.w;
        }
    }
    for (int w = t; w < 750; w += 512) {
        int e2 = w / 15, pi = w - e2 * 15;
        int e = e2 >> 1, ci = e2 & 1;
        int ey = e / 5 - 2, ex = e % 5 - 2;
        int c0 = pi * 10;
        float s = 0.f;
        for (int dqy = -1; dqy <= 1; ++dqy)
            for (int dqx = -1; dqx <= 1; ++dqx) {
                int dsy = ey - dqy, dsx = ex - dqx;
                if (dsy < -1 || dsy > 1 || dsx < -1 || dsx > 1) continue;
                const float* wr = w_r + ((dqy + 1) * 3 + (dqx + 1)) * 150;
                const float* wp = w0 + (((dsy + 1) * 3 + (dsx + 1)) * 2 + ci) * 150;
                for (int c = c0; c < c0 + 10; ++c) s += wr[c] * wp[c];
            }
        wtmp[w] = s;
    }
    if (t < 90) {
        int d = t / 10, pi = t - d * 10, c0 = pi * 15;
        float s = 0.f;
        for (int c = c0; c < c0 + 15; ++c) s += w_r[d * 150 + c] * b0[c];
        wtmp[750 + t] = s;
    }
    __syncthreads();
    if (t < 50) {
        float s = 0.f;
        for (int i = 0; i < 15; ++i) s += wtmp[t * 15 + i];
        wfin[t] = s;
    } else if (t < 59) {
        int d = t - 50;
        float s = 0.f;
        for (int i = 0; i < 10; ++i) s += wtmp[750 + d * 10 + i];
        wfin[t] = s;
    } else if (t == 59) {
        float s = 0.f;
        for (int j = 0; j < 90; ++j) s += wtmp[750 + j];
        wfin[59] = s;
    }
    __syncthreads();

    {
        float W5a[25], W5b[25];
        #pragma unroll
        for (int e = 0; e < 25; ++e) { W5a[e] = wfin[e * 2]; W5b[e] = wfin[e * 2 + 1]; }
        float Btot = wfin[59];
        #pragma unroll
        for (int p = 0; p < 8; ++p) {
            int xx = cbP + p;
            float acc = Btot;
            #pragma unroll
            for (int ey = 0; ey < 5; ++ey)
                #pragma unroll
                for (int ex = 0; ex < 5; ++ex) {
                    int xi = (rowP + ey) * XROW + (xx + ex);
                    acc = fmaf(xs0[xi], W5a[ey * 5 + ex], acc);
                    acc = fmaf(xs1[xi], W5b[ey * 5 + ex], acc);
                }
            rs[(rowP + 1) * VROW + (xx + 1)] = acc;
        }
    }
    __syncthreads();

    for (int wi = t; wi < 1040; wi += 512) {
        int qi = wi >> 2, ch = wi & 3;
        int qy, qx;
        if (qi < 66)       { qy = -1; qx = qi - 1; }
        else if (qi < 132) { qy = 64; qx = qi - 67; }
        else if (qi < 196) { qx = -1; qy = qi - 132; }
        else               { qx = 64; qy = qi - 196; }
        int c0 = (ch < 2) ? ch * 38 : 76 + (ch - 2) * 37;
        int c1 = (ch < 2) ? c0 + 38 : c0 + 37;
        float sdq[9];
        #pragma unroll
        for (int d = 0; d < 9; ++d) sdq[d] = 0.f;
        for (int c = c0; c < c1; ++c) {
            float hc = 0.f;
            #pragma unroll
            for (int ky = 0; ky < 3; ++ky)
                #pragma unroll
                for (int kx = 0; kx < 3; ++kx) {
                    int xi = (qy + ky + 1) * XROW + (qx + kx + 1);
                    const float* wp = &w0[((ky * 3 + kx) * 2) * 150 + c];
                    hc = fmaf(xs0[xi], wp[0], hc);
                    hc = fmaf(xs1[xi], wp[150], hc);
                }
            #pragma unroll
            for (int d = 0; d < 9; ++d) sdq[d] = fmaf(w_r[d * 150 + c], hc, sdq[d]);
        }
        #pragma unroll
        for (int d = 0; d < 9; ++d) {
            int dy = d / 3 - 1, dx = d % 3 - 1;
            int py = qy - dy, px = qx - dx;
            if (py >= 0 && py < 64 && px >= 0 && px < 64) {
                float corr = sdq[d] + (ch == 0 ? wfin[50 + d] : 0.f);
                atomicAdd(&rs[(py + 1) * VROW + (px + 1)], -corr);
            }
        }
    }
    __syncthreads();

    // ================= K-LOOP (this WG's 32 rows, 4 px/thread) =============
    const int rowg = r0 + (t >> 4);      // global row 0..63
    const int cb   = (t & 15) << 2;      // 0,4,...,60
    const int lr   = (t >> 4) + 1;       // local v row 1..32
    const int halo_lr = h ? 0 : 33;      // exchanged halo row (other one stays 0)
    const bool is_pub = h ? (t < 16) : (t >= 496);  // boundary wave

    // Rsw precompute + first step (w_q)
    float Rsw[4][10];
    {
        float rwin[3][6];
        #pragma unroll
        for (int i = 0; i < 3; ++i) {
            const float* rp = &rs[(rowg + i) * VROW + cb];
            #pragma unroll
            for (int j = 0; j < 6; ++j) rwin[i][j] = rp[j];
        }
        float vmax[4];
        #pragma unroll
        for (int a = 0; a < 10; ++a) {
            #pragma unroll
            for (int p = 0; p < 4; ++p) {
                float accR = 0.f, accQ = 0.f;
                #pragma unroll
                for (int d = 0; d < 9; ++d) {
                    float rv = rwin[d / 3][p + d % 3];
                    accR = fmaf(w_sw[d * 20 + a], rv, accR);
                    accQ = fmaf(w_q[d * 20 + a],  rv, accQ);
                }
                Rsw[p][a] = accR;
                vmax[p] = (a == 0) ? accQ : fmaxf(vmax[p], accQ);
            }
        }
        #pragma unroll
        for (int p = 0; p < 4; ++p)
            vloc[0 * VLSTR + lr * VROW + (cb + p + 1)] = vmax[p];
        // publish v_1 boundary: flag=1, slot=1
        if (is_pub) {
            float4* dst = (float4*)(wsf + (me * 2 + 1) * 64) + (t & 15);
            *dst = make_float4(vmax[0], vmax[1], vmax[2], vmax[3]);
            __threadfence();
            __hip_atomic_store(flags + me, 1, __ATOMIC_RELEASE, __HIP_MEMORY_SCOPE_AGENT);
        }
    }
    __syncthreads();

    int cur = 0;
    for (int it = 0; it < K - 1; ++it) {
        // fetch partner boundary of v_{it+1}: flag >= it+1, slot (it+1)&1
        if (t < 16) {
            while (__hip_atomic_load(flags + partner, __ATOMIC_ACQUIRE,
                                     __HIP_MEMORY_SCOPE_AGENT) < it + 1) {}
            float4 hv = *((const float4*)(wsf + (partner * 2 + ((it + 1) & 1)) * 64) + t);
            float* dr = &vloc[cur * VLSTR + halo_lr * VROW + 1 + t * 4];
            dr[0] = hv.x; dr[1] = hv.y; dr[2] = hv.z; dr[3] = hv.w;
        }
        __syncthreads();

        float vwin[3][6];
        #pragma unroll
        for (int i = 0; i < 3; ++i) {
            const float* vb = &vloc[cur * VLSTR + (lr - 1 + i) * VROW + cb];
            #pragma unroll
            for (int j = 0; j < 6; ++j) vwin[i][j] = vb[j];
        }
        float acc[4][10];
        #pragma unroll
        for (int p = 0; p < 4; ++p)
            #pragma unroll
            for (int a = 0; a < 10; ++a) acc[p][a] = Rsw[p][a];
        #pragma unroll
        for (int d = 0; d < 9; ++d) {
            float4 wA = swv4[d * 3 + 0];
            float4 wB = swv4[d * 3 + 1];
            float4 wC = swv4[d * 3 + 2];
            #pragma unroll
            for (int p = 0; p < 4; ++p) {
                float vv = vwin[d / 3][p + d % 3];
                acc[p][0] = fmaf(wA.x, vv, acc[p][0]);
                acc[p][1] = fmaf(wA.y, vv, acc[p][1]);
                acc[p][2] = fmaf(wA.z, vv, acc[p][2]);
                acc[p][3] = fmaf(wA.w, vv, acc[p][3]);
                acc[p][4] = fmaf(wB.x, vv, acc[p][4]);
                acc[p][5] = fmaf(wB.y, vv, acc[p][5]);
                acc[p][6] = fmaf(wB.z, vv, acc[p][6]);
                acc[p][7] = fmaf(wB.w, vv, acc[p][7]);
                acc[p][8] = fmaf(wC.x, vv, acc[p][8]);
                acc[p][9] = fmaf(wC.y, vv, acc[p][9]);
            }
        }
        int nxt = cur ^ 1;
        float vmax[4];
        #pragma unroll
        for (int p = 0; p < 4; ++p) {
            float m = acc[p][0];
            #pragma unroll
            for (int a = 1; a < 10; ++a) m = fmaxf(m, acc[p][a]);
            vmax[p] = m;
            vloc[nxt * VLSTR + lr * VROW + (cb + p + 1)] = m;
        }
        // publish v_{it+2}: flag=it+2, slot (it+2)&1 = it&1
        if (is_pub) {
            float4* dst = (float4*)(wsf + (me * 2 + (it & 1)) * 64) + (t & 15);
            *dst = make_float4(vmax[0], vmax[1], vmax[2], vmax[3]);
            __threadfence();
            __hip_atomic_store(flags + me, it + 2, __ATOMIC_RELEASE, __HIP_MEMORY_SCOPE_AGENT);
        }
        __syncthreads();
        cur = nxt;
    }

    // fetch halo of v_K: flag >= K, slot K&1
    if (t < 16) {
        while (__hip_atomic_load(flags + partner, __ATOMIC_ACQUIRE,
                                 __HIP_MEMORY_SCOPE_AGENT) < K) {}
        float4 hv = *((const float4*)(wsf + (partner * 2 + (K & 1)) * 64) + t);
        float* dr = &vloc[cur * VLSTR + halo_lr * VROW + 1 + t * 4];
        dr[0] = hv.x; dr[1] = hv.y; dr[2] = hv.z; dr[3] = hv.w;
    }
    __syncthreads();

    // ---- final step with w_sw2: q -> global, gather (S1,S2) ----
    const int s1 = S1[b], s2 = S2[b];
    const bool owner = ((s1 >> 5) == h);
    {
        float rwin[3][6], vwin[3][6];
        #pragma unroll
        for (int i = 0; i < 3; ++i) {
            const float* rp = &rs[(rowg + i) * VROW + cb];
            const float* vb = &vloc[cur * VLSTR + (lr - 1 + i) * VROW + cb];
            #pragma unroll
            for (int j = 0; j < 6; ++j) { rwin[i][j] = rp[j]; vwin[i][j] = vb[j]; }
        }
        float qv[4][10];
        #pragma unroll
        for (int a = 0; a < 10; ++a) {
            #pragma unroll
            for (int p = 0; p < 4; ++p) {
                float acc = 0.f;
                #pragma unroll
                for (int d = 0; d < 9; ++d) {
                    acc = fmaf(w_sw2[d * 20 + a],      rwin[d / 3][p + d % 3], acc);
                    acc = fmaf(w_sw2[d * 20 + 10 + a], vwin[d / 3][p + d % 3], acc);
                }
                qv[p][a] = acc;
            }
        }
        float4* qp4 = (float4*)(out + 2048 + ((size_t)((b * 64 + rowg) * 64 + cb)) * 10);
        #pragma unroll
        for (int g = 0; g < 10; ++g) {
            int e = g * 4;
            qp4[g] = make_float4(qv[e / 10][e % 10], qv[(e + 1) / 10][(e + 1) % 10],
                                 qv[(e + 2) / 10][(e + 2) % 10], qv[(e + 3) / 10][(e + 3) % 10]);
        }
        if (owner && rowg == s1) {
            #pragma unroll
            for (int p = 0; p < 4; ++p)
                if (s2 == cb + p) {
                    #pragma unroll
                    for (int a = 0; a < 10; ++a) qsel[a] = qv[p][a];
                }
        }
    }
    __syncthreads();

    if (owner && t == 0) {
        float logits[8];
        float m = -1e30f;
        #pragma unroll
        for (int j = 0; j < 8; ++j) {
            float s = 0.f;
            #pragma unroll
            for (int a = 0; a < 10; ++a) s += qsel[a] * w_dense[a * 8 + j];
            logits[j] = s;
            m = fmaxf(m, s);
        }
        float sum = 0.f;
        float e[8];
        #pragma unroll
        for (int j = 0; j < 8; ++j) { e[j] = expf(logits[j] - m); sum += e[j]; }
        float inv = 1.f / sum;
        #pragma unroll
        for (int j = 0; j < 8; ++j) {
            out[b * 8 + j] = logits[j];
            out[1024 + b * 8 + j] = e[j] * inv;
        }
    }
    if (owner && t < 10) out[5244928 + b * 10 + t] = qsel[t];
}

extern "C" void kernel_launch(void* const* d_in, const int* in_sizes, int n_in,
                              void* d_out, int out_size, void* d_ws, size_t ws_size,
                              hipStream_t stream) {
    const float* x      = (const float*)d_in[0];
    const int*   S1     = (const int*)d_in[1];
    const int*   S2     = (const int*)d_in[2];
    const int*   VInum  = (const int*)d_in[3];
    const float* w0     = (const float*)d_in[4];
    const float* b0     = (const float*)d_in[5];
    const float* w_r    = (const float*)d_in[6];
    const float* w_q    = (const float*)d_in[7];
    const float* w_sw   = (const float*)d_in[8];
    const float* w_sw2  = (const float*)d_in[9];
    const float* w_dense= (const float*)d_in[10];
    float* out = (float*)d_out;
    float* wsf = (float*)d_ws;

    init_flags<<<1, 256, 0, stream>>>((int*)d_ws + FLAG_OFF);
    vin_kernel<<<256, 512, 0, stream>>>(x, S1, S2, VInum, w0, b0, w_r, w_q,
                                        w_sw, w_sw2, w_dense, wsf, out);
}

// Round 9
// 318.000 us; speedup vs baseline: 1.7455x; 1.7455x over previous
//
#include <hip/hip_runtime.h>
#include <math.h>

// VIN forward on MI355X — single fused kernel (128 WGs x 512 thr, 8 px/thread).
// Sizes: N=128, H=W=64, CH_I=2, CH_H=150, CH_Q=10, N_ACT=8, VInum=36.
//
// R8 -> R9 changes (retreat to R5 trunk + R8's validated K-loop body):
//  * Split-WG + mailbox abandoned: R8 showed device-scope acquire-per-poll /
//    release-per-publish costs ~7us/iter (L2 inv/wb on non-coherent XCD L2s),
//    and the LDS pad was DCE'd so WGs packed 2/CU anyway.
//  * Weights read as float4 from transposed layout swvT[a][d-quads]:
//    2x ds_read_b128 + 1x ds_read_b32 per action = 30 LDS instrs/thread/iter
//    (was 90 scalar b32 — the allocator-refold R5/R6/R7 could not defeat).
//    16B-aligned, wave-uniform address -> broadcast, conflict-free.
//  * acc init folded into tap 0 (fmaf into Rsw) — kills 80 v_mov/iter.
//  * a-outer loop keeps live set ~130 regs (R5's proven shape).

#define XROW 69
#define VROW 67
#define VSTR (66 * VROW)          // 4422 floats per v buffer

__global__ void
__attribute__((amdgpu_flat_work_group_size(512, 512)))
__attribute__((amdgpu_waves_per_eu(2, 2)))
vin_kernel(const float* __restrict__ x,
           const int* __restrict__ S1,
           const int* __restrict__ S2,
           const int* __restrict__ VInum,
           const float* __restrict__ w0,
           const float* __restrict__ b0,
           const float* __restrict__ w_r,
           const float* __restrict__ w_q,
           const float* __restrict__ w_sw,
           const float* __restrict__ w_sw2,
           const float* __restrict__ w_dense,
           float* __restrict__ out) {
    const int b = blockIdx.x;
    const int t = threadIdx.x;

    __shared__ float xs0[68 * XROW];     // x ch0, [y+2][x+2], 2-halo of zeros
    __shared__ float xs1[68 * XROW];     // x ch1
    __shared__ float rs[66 * VROW];      // r with 1-halo of zeros
    __shared__ float vpool[2 * VSTR];    // v double buffer, 1-halo of zeros
    __shared__ float wtmp[840];          // W5 partials [0..749], B partials [750..839]
    __shared__ float wfin[60];           // W5[50], B[9], Btot
    __shared__ float swvT[120];          // w_sw v-part TRANSPOSED: [a][d], row stride 12
    __shared__ float qsel[10];

    // ---- zero LDS (halos must be 0) ----
    for (int i = t; i < 68 * XROW; i += 512) { xs0[i] = 0.f; xs1[i] = 0.f; }
    for (int i = t; i < 66 * VROW; i += 512) rs[i] = 0.f;
    for (int i = t; i < 2 * VSTR; i += 512) vpool[i] = 0.f;
    if (t < 120) {
        int a = t / 12, d = t % 12;
        swvT[t] = (d < 9) ? w_sw[d * 20 + 10 + a] : 0.f;
    }
    __syncthreads();

    const int row = t >> 3;          // 0..63
    const int cb  = (t & 7) << 3;    // 0,8,...,56  (8 px per thread)

    // ---- stage x into split planes (16 contiguous floats = 4x float4) ----
    {
        const float* xb = x + (size_t)b * 64 * 64 * 2;
        const float4* xp = (const float4*)(xb + (row * 64 + cb) * 2);
        #pragma unroll
        for (int g = 0; g < 4; ++g) {
            float4 v4 = xp[g];
            int px = cb + g * 2;
            xs0[(row + 2) * XROW + px + 2] = v4.x;
            xs1[(row + 2) * XROW + px + 2] = v4.y;
            xs0[(row + 2) * XROW + px + 3] = v4.z;
            xs1[(row + 2) * XROW + px + 3] = v4.w;
        }
    }
    // ---- W5 compose partials: 50 entries x 15 channel-chunks (750 items) ----
    for (int w = t; w < 750; w += 512) {
        int e2 = w / 15, pi = w - e2 * 15;
        int e = e2 >> 1, ci = e2 & 1;
        int ey = e / 5 - 2, ex = e % 5 - 2;
        int c0 = pi * 10;
        float s = 0.f;
        for (int dqy = -1; dqy <= 1; ++dqy)
            for (int dqx = -1; dqx <= 1; ++dqx) {
                int dsy = ey - dqy, dsx = ex - dqx;
                if (dsy < -1 || dsy > 1 || dsx < -1 || dsx > 1) continue;
                const float* wr = w_r + ((dqy + 1) * 3 + (dqx + 1)) * 150;
                const float* wp = w0 + (((dsy + 1) * 3 + (dsx + 1)) * 2 + ci) * 150;
                for (int c = c0; c < c0 + 10; ++c) s += wr[c] * wp[c];
            }
        wtmp[w] = s;
    }
    if (t < 90) {
        int d = t / 10, pi = t - d * 10, c0 = pi * 15;
        float s = 0.f;
        for (int c = c0; c < c0 + 15; ++c) s += w_r[d * 150 + c] * b0[c];
        wtmp[750 + t] = s;
    }
    __syncthreads();
    if (t < 50) {
        float s = 0.f;
        for (int i = 0; i < 15; ++i) s += wtmp[t * 15 + i];
        wfin[t] = s;
    } else if (t < 59) {
        int d = t - 50;
        float s = 0.f;
        for (int i = 0; i < 10; ++i) s += wtmp[750 + d * 10 + i];
        wfin[t] = s;
    } else if (t == 59) {
        float s = 0.f;
        for (int j = 0; j < 90; ++j) s += wtmp[750 + j];
        wfin[59] = s;
    }
    __syncthreads();

    // ---- r interior via composed 5x5 conv ----
    {
        float W5a[25], W5b[25];
        #pragma unroll
        for (int e = 0; e < 25; ++e) { W5a[e] = wfin[e * 2]; W5b[e] = wfin[e * 2 + 1]; }
        float Btot = wfin[59];
        #pragma unroll
        for (int p = 0; p < 8; ++p) {
            int xx = cb + p;
            float acc = Btot;
            #pragma unroll
            for (int ey = 0; ey < 5; ++ey)
                #pragma unroll
                for (int ex = 0; ex < 5; ++ex) {
                    int xi = (row + ey) * XROW + (xx + ex);
                    acc = fmaf(xs0[xi], W5a[ey * 5 + ex], acc);
                    acc = fmaf(xs1[xi], W5b[ey * 5 + ex], acc);
                }
            rs[(row + 1) * VROW + (xx + 1)] = acc;
        }
    }
    __syncthreads();

    // ---- border fix: 260 virtual-h positions x 4 channel chunks = 1040 items ----
    for (int wi = t; wi < 1040; wi += 512) {
        int qi = wi >> 2, ch = wi & 3;
        int qy, qx;
        if (qi < 66)       { qy = -1; qx = qi - 1; }
        else if (qi < 132) { qy = 64; qx = qi - 67; }
        else if (qi < 196) { qx = -1; qy = qi - 132; }
        else               { qx = 64; qy = qi - 196; }
        int c0 = (ch < 2) ? ch * 38 : 76 + (ch - 2) * 37;
        int c1 = (ch < 2) ? c0 + 38 : c0 + 37;
        float sdq[9];
        #pragma unroll
        for (int d = 0; d < 9; ++d) sdq[d] = 0.f;
        for (int c = c0; c < c1; ++c) {
            float hc = 0.f;
            #pragma unroll
            for (int ky = 0; ky < 3; ++ky)
                #pragma unroll
                for (int kx = 0; kx < 3; ++kx) {
                    int xi = (qy + ky + 1) * XROW + (qx + kx + 1);
                    const float* wp = &w0[((ky * 3 + kx) * 2) * 150 + c];
                    hc = fmaf(xs0[xi], wp[0], hc);
                    hc = fmaf(xs1[xi], wp[150], hc);
                }
            #pragma unroll
            for (int d = 0; d < 9; ++d) sdq[d] = fmaf(w_r[d * 150 + c], hc, sdq[d]);
        }
        #pragma unroll
        for (int d = 0; d < 9; ++d) {
            int dy = d / 3 - 1, dx = d % 3 - 1;
            int py = qy - dy, px = qx - dx;
            if (py >= 0 && py < 64 && px >= 0 && px < 64) {
                float corr = sdq[d] + (ch == 0 ? wfin[50 + d] : 0.f);
                atomicAdd(&rs[(py + 1) * VROW + (px + 1)], -corr);
            }
        }
    }
    __syncthreads();

    const int K = VInum[0];

    // ---- Rsw precompute (loop-invariant r-part of w_sw conv) + first step (w_q) ----
    float Rsw[8][10];
    {
        float rwin[3][10];
        #pragma unroll
        for (int i = 0; i < 3; ++i) {
            const float* rp = &rs[(row + i) * VROW + cb];
            #pragma unroll
            for (int j = 0; j < 10; ++j) rwin[i][j] = rp[j];
        }
        float vmax[8];
        #pragma unroll
        for (int a = 0; a < 10; ++a) {
            #pragma unroll
            for (int p = 0; p < 8; ++p) {
                float accR = 0.f, accQ = 0.f;
                #pragma unroll
                for (int d = 0; d < 9; ++d) {
                    float rv = rwin[d / 3][p + d % 3];
                    accR = fmaf(w_sw[d * 20 + a], rv, accR);
                    accQ = fmaf(w_q[d * 20 + a],  rv, accQ);
                }
                Rsw[p][a] = accR;
                vmax[p] = (a == 0) ? accQ : fmaxf(vmax[p], accQ);
            }
        }
        #pragma unroll
        for (int p = 0; p < 8; ++p)
            vpool[0 * VSTR + (row + 1) * VROW + (cb + p + 1)] = vmax[p];
    }
    __syncthreads();

    // ---- K-1 shared-weight VI steps, double-buffered v ----
    int cur = 0;
    for (int it = 0; it < K - 1; ++it) {
        const float* vb = &vpool[cur * VSTR + row * VROW + cb];
        float vwin[3][10];
        #pragma unroll
        for (int i = 0; i < 3; ++i)
            #pragma unroll
            for (int j = 0; j < 10; ++j) vwin[i][j] = vb[i * VROW + j];
        int nxt = cur ^ 1;
        float vmax[8];
        #pragma unroll
        for (int a = 0; a < 10; ++a) {
            float4 wA = *(const float4*)&swvT[a * 12];      // taps 0..3
            float4 wB = *(const float4*)&swvT[a * 12 + 4];  // taps 4..7
            float  w8 = swvT[a * 12 + 8];                   // tap 8
            #pragma unroll
            for (int p = 0; p < 8; ++p) {
                float s = fmaf(wA.x, vwin[0][p + 0], Rsw[p][a]);
                s = fmaf(wA.y, vwin[0][p + 1], s);
                s = fmaf(wA.z, vwin[0][p + 2], s);
                s = fmaf(wA.w, vwin[1][p + 0], s);
                s = fmaf(wB.x, vwin[1][p + 1], s);
                s = fmaf(wB.y, vwin[1][p + 2], s);
                s = fmaf(wB.z, vwin[2][p + 0], s);
                s = fmaf(wB.w, vwin[2][p + 1], s);
                s = fmaf(w8,   vwin[2][p + 2], s);
                vmax[p] = (a == 0) ? s : fmaxf(vmax[p], s);
            }
        }
        #pragma unroll
        for (int p = 0; p < 8; ++p)
            vpool[nxt * VSTR + (row + 1) * VROW + (cb + p + 1)] = vmax[p];
        cur = nxt;
        __syncthreads();
    }

    // ---- final step with w_sw2: q -> global, gather (S1,S2) ----
    const int s1 = S1[b], s2 = S2[b];
    {
        float rwin[3][10], vwin[3][10];
        #pragma unroll
        for (int i = 0; i < 3; ++i) {
            const float* rp = &rs[(row + i) * VROW + cb];
            const float* vb = &vpool[cur * VSTR + (row + i) * VROW + cb];
            #pragma unroll
            for (int j = 0; j < 10; ++j) { rwin[i][j] = rp[j]; vwin[i][j] = vb[j]; }
        }
        float qv[8][10];
        #pragma unroll
        for (int a = 0; a < 10; ++a) {
            #pragma unroll
            for (int p = 0; p < 8; ++p) {
                float acc = 0.f;
                #pragma unroll
                for (int d = 0; d < 9; ++d) {
                    acc = fmaf(w_sw2[d * 20 + a],      rwin[d / 3][p + d % 3], acc);
                    acc = fmaf(w_sw2[d * 20 + 10 + a], vwin[d / 3][p + d % 3], acc);
                }
                qv[p][a] = acc;
            }
        }
        // store q: 80 contiguous floats (8 px x 10 actions), 16B-aligned
        {
            float4* qp4 = (float4*)(out + 2048 + ((size_t)((b * 64 + row) * 64 + cb)) * 10);
            #pragma unroll
            for (int g = 0; g < 20; ++g)
                qp4[g] = make_float4(qv[(g * 4) / 10][(g * 4) % 10],
                                     qv[(g * 4 + 1) / 10][(g * 4 + 1) % 10],
                                     qv[(g * 4 + 2) / 10][(g * 4 + 2) % 10],
                                     qv[(g * 4 + 3) / 10][(g * 4 + 3) % 10]);
        }
        if (row == s1) {
            #pragma unroll
            for (int p = 0; p < 8; ++p)
                if (s2 == cb + p) {
                    #pragma unroll
                    for (int a = 0; a < 10; ++a) qsel[a] = qv[p][a];
                }
        }
    }
    __syncthreads();

    // ---- dense + softmax (thread 0), q_out (threads 0..9) ----
    if (t == 0) {
        float logits[8];
        float m = -1e30f;
        #pragma unroll
        for (int j = 0; j < 8; ++j) {
            float s = 0.f;
            #pragma unroll
            for (int a = 0; a < 10; ++a) s += qsel[a] * w_dense[a * 8 + j];
            logits[j] = s;
            m = fmaxf(m, s);
        }
        float sum = 0.f;
        float e[8];
        #pragma unroll
        for (int j = 0; j < 8; ++j) { e[j] = expf(logits[j] - m); sum += e[j]; }
        float inv = 1.f / sum;
        #pragma unroll
        for (int j = 0; j < 8; ++j) {
            out[b * 8 + j] = logits[j];
            out[1024 + b * 8 + j] = e[j] * inv;
        }
    }
    if (t < 10) out[5244928 + b * 10 + t] = qsel[t];
}

extern "C" void kernel_launch(void* const* d_in, const int* in_sizes, int n_in,
                              void* d_out, int out_size, void* d_ws, size_t ws_size,
                              hipStream_t stream) {
    const float* x      = (const float*)d_in[0];
    const int*   S1     = (const int*)d_in[1];
    const int*   S2     = (const int*)d_in[2];
    const int*   VInum  = (const int*)d_in[3];
    const float* w0     = (const float*)d_in[4];
    const float* b0     = (const float*)d_in[5];
    const float* w_r    = (const float*)d_in[6];
    const float* w_q    = (const float*)d_in[7];
    const float* w_sw   = (const float*)d_in[8];
    const float* w_sw2  = (const float*)d_in[9];
    const float* w_dense= (const float*)d_in[10];
    float* out = (float*)d_out;

    vin_kernel<<<128, 512, 0, stream>>>(x, S1, S2, VInum, w0, b0, w_r, w_q,
                                        w_sw, w_sw2, w_dense, out);
}

// Round 10
// 200.144 us; speedup vs baseline: 2.7734x; 1.5889x over previous
//
#include <hip/hip_runtime.h>
#include <math.h>

// VIN forward on MI355X — single fused kernel (128 WGs x 512 thr, 8 px/thread).
// Sizes: N=128, H=W=64, CH_I=2, CH_H=150, CH_Q=10, N_ACT=8, VInum=36.
//
// R9 -> R10 changes:
//  * K-loop reverted to R5's exact scalar form (90 ds_read_b32 weight stream):
//    proven fastest (241us vs 254 b128 / 280 packed). The scalar stream
//    pipelines through the 720-FMA body; wide loads cluster waits.
//  * Prologue rewritten: the border-fix pass (~1.2M scattered global loads +
//    LDS atomics per WG) is GONE. r = conv3(conv3(x)+b0) with SAME padding is
//    a 5x5 stencil whose weights vary only by edge class; d in {-1,0,1} means
//    the inner zero-pad bites only at distance 0 -> 9 classes (T/M/B x L/M/R).
//    Precompute P[d][25][2] partials (162 dots of 150) -> class subset-sums
//    W5c[9][51] (50 weights + bias) -> one stencil pass computes r everywhere.

#define XROW 69
#define VROW 67
#define VSTR (66 * VROW)          // 4422 floats per v buffer

__global__ void
__attribute__((amdgpu_flat_work_group_size(512, 512)))
__attribute__((amdgpu_waves_per_eu(2, 2)))
vin_kernel(const float* __restrict__ x,
           const int* __restrict__ S1,
           const int* __restrict__ S2,
           const int* __restrict__ VInum,
           const float* __restrict__ w0,
           const float* __restrict__ b0,
           const float* __restrict__ w_r,
           const float* __restrict__ w_q,
           const float* __restrict__ w_sw,
           const float* __restrict__ w_sw2,
           const float* __restrict__ w_dense,
           float* __restrict__ out) {
    const int b = blockIdx.x;
    const int t = threadIdx.x;

    __shared__ float xs0[68 * XROW];     // x ch0, [y+2][x+2], 2-halo of zeros
    __shared__ float xs1[68 * XROW];     // x ch1
    __shared__ float rs[66 * VROW];      // r with 1-halo of zeros
    __shared__ float vpool[2 * VSTR];    // v double buffer, 1-halo of zeros
    __shared__ float wtA[1620];          // P chunk partials: 162 entries x 10
    __shared__ float Pp[450];            // P[d][e5x5][ci], zero-init (162 filled)
    __shared__ float Bt[90];             // bias chunk partials: 9 d x 10
    __shared__ float Bv[9];              // B[d] = w_r[d].b0
    __shared__ float W5c[459];           // 9 classes x (50 weights + bias)
    __shared__ float swv[90];            // w_sw v-part, [d][a]
    __shared__ float qsel[10];

    // ---- zero LDS (halos must be 0; Pp must be 0 for invalid combos) ----
    for (int i = t; i < 68 * XROW; i += 512) { xs0[i] = 0.f; xs1[i] = 0.f; }
    for (int i = t; i < 66 * VROW; i += 512) rs[i] = 0.f;
    for (int i = t; i < 2 * VSTR; i += 512) vpool[i] = 0.f;
    if (t < 450) Pp[t] = 0.f;
    if (t < 90) swv[t] = w_sw[(t / 10) * 20 + 10 + (t % 10)];
    __syncthreads();

    const int row = t >> 3;          // 0..63
    const int cb  = (t & 7) << 3;    // 0,8,...,56  (8 px per thread)

    // ---- stage x into split planes (16 contiguous floats = 4x float4) ----
    {
        const float* xb = x + (size_t)b * 64 * 64 * 2;
        const float4* xp = (const float4*)(xb + (row * 64 + cb) * 2);
        #pragma unroll
        for (int g = 0; g < 4; ++g) {
            float4 v4 = xp[g];
            int px = cb + g * 2;
            xs0[(row + 2) * XROW + px + 2] = v4.x;
            xs1[(row + 2) * XROW + px + 2] = v4.y;
            xs0[(row + 2) * XROW + px + 3] = v4.z;
            xs1[(row + 2) * XROW + px + 3] = v4.w;
        }
    }
    // ---- round A: P chunk partials (1620 items) + bias chunks (90) ----
    for (int idx = t; idx < 1620; idx += 512) {
        int entry = idx / 10, ch = idx - entry * 10;
        int d = entry / 18, rem = entry % 18;
        int uu = rem >> 1, ci = rem & 1;
        int c0 = ch * 15;
        const float* wr = w_r + d * 150;
        const float* wp = w0 + (uu * 2 + ci) * 150;
        float s = 0.f;
        for (int c = c0; c < c0 + 15; ++c) s += wr[c] * wp[c];
        wtA[idx] = s;
    }
    if (t < 90) {
        int d = t / 10, ch = t - d * 10, c0 = ch * 15;
        float s = 0.f;
        for (int c = c0; c < c0 + 15; ++c) s += w_r[d * 150 + c] * b0[c];
        Bt[t] = s;
    }
    __syncthreads();
    // ---- round B: reduce P entries (162) and B (9) ----
    if (t < 162) {
        float s = 0.f;
        #pragma unroll
        for (int i = 0; i < 10; ++i) s += wtA[t * 10 + i];
        int d = t / 18, rem = t % 18;
        int uu = rem >> 1, ci = rem & 1;
        int dy = d / 3 - 1, dx = d % 3 - 1;
        int uy = uu / 3 - 1, ux = uu % 3 - 1;
        int eidx = (dy + uy + 2) * 5 + (dx + ux + 2);
        Pp[d * 50 + eidx * 2 + ci] = s;
    } else if (t >= 256 && t < 265) {
        int d = t - 256;
        float s = 0.f;
        #pragma unroll
        for (int i = 0; i < 10; ++i) s += Bt[d * 10 + i];
        Bv[d] = s;
    }
    __syncthreads();
    // ---- round C: class subset-sums W5c[9][51] ----
    if (t < 459) {
        int cls = t / 51, j = t - cls * 51;
        int cy = cls / 3, cx = cls % 3;
        float s = 0.f;
        #pragma unroll
        for (int d = 0; d < 9; ++d) {
            int dy = d / 3 - 1, dx = d % 3 - 1;
            bool ok = (cy == 0 || (cy == 1 ? dy >= 0 : dy <= 0)) &&
                      (cx == 0 || (cx == 1 ? dx >= 0 : dx <= 0));
            if (ok) s += (j < 50) ? Pp[d * 50 + j] : Bv[d];
        }
        W5c[t] = s;
    }
    __syncthreads();

    // ---- r everywhere via class-weighted 5x5 stencil ----
    {
        int cy = (row == 0) ? 1 : (row == 63) ? 2 : 0;
        #pragma unroll
        for (int p = 0; p < 8; ++p) {
            int xx = cb + p;
            int cx = (xx == 0) ? 1 : (xx == 63) ? 2 : 0;
            const float* Wp = &W5c[(cy * 3 + cx) * 51];
            float acc = Wp[50];
            #pragma unroll
            for (int e = 0; e < 25; ++e) {
                int xi = (row + e / 5) * XROW + (xx + e % 5);
                acc = fmaf(xs0[xi], Wp[e * 2], acc);
                acc = fmaf(xs1[xi], Wp[e * 2 + 1], acc);
            }
            rs[(row + 1) * VROW + (xx + 1)] = acc;
        }
    }
    __syncthreads();

    const int K = VInum[0];

    // ---- Rsw precompute (loop-invariant r-part of w_sw conv) + first step (w_q) ----
    float Rsw[8][10];
    {
        float rwin[3][10];
        #pragma unroll
        for (int i = 0; i < 3; ++i) {
            const float* rp = &rs[(row + i) * VROW + cb];
            #pragma unroll
            for (int j = 0; j < 10; ++j) rwin[i][j] = rp[j];
        }
        float vmax[8];
        #pragma unroll
        for (int a = 0; a < 10; ++a) {
            #pragma unroll
            for (int p = 0; p < 8; ++p) {
                float accR = 0.f, accQ = 0.f;
                #pragma unroll
                for (int d = 0; d < 9; ++d) {
                    float rv = rwin[d / 3][p + d % 3];
                    accR = fmaf(w_sw[d * 20 + a], rv, accR);
                    accQ = fmaf(w_q[d * 20 + a],  rv, accQ);
                }
                Rsw[p][a] = accR;
                vmax[p] = (a == 0) ? accQ : fmaxf(vmax[p], accQ);
            }
        }
        #pragma unroll
        for (int p = 0; p < 8; ++p)
            vpool[0 * VSTR + (row + 1) * VROW + (cb + p + 1)] = vmax[p];
    }
    __syncthreads();

    // ---- K-1 shared-weight VI steps, double-buffered v (R5 exact form) ----
    int cur = 0;
    for (int it = 0; it < K - 1; ++it) {
        const float* vb = &vpool[cur * VSTR + row * VROW + cb];
        float vwin[3][10];
        #pragma unroll
        for (int i = 0; i < 3; ++i)
            #pragma unroll
            for (int j = 0; j < 10; ++j) vwin[i][j] = vb[i * VROW + j];
        int nxt = cur ^ 1;
        float vmax[8];
        #pragma unroll
        for (int a = 0; a < 10; ++a) {
            #pragma unroll
            for (int p = 0; p < 8; ++p) {
                float acc = Rsw[p][a];
                #pragma unroll
                for (int d = 0; d < 9; ++d)
                    acc = fmaf(swv[d * 10 + a], vwin[d / 3][p + d % 3], acc);
                vmax[p] = (a == 0) ? acc : fmaxf(vmax[p], acc);
            }
        }
        #pragma unroll
        for (int p = 0; p < 8; ++p)
            vpool[nxt * VSTR + (row + 1) * VROW + (cb + p + 1)] = vmax[p];
        cur = nxt;
        __syncthreads();
    }

    // ---- final step with w_sw2: q -> global, gather (S1,S2) ----
    const int s1 = S1[b], s2 = S2[b];
    {
        float rwin[3][10], vwin[3][10];
        #pragma unroll
        for (int i = 0; i < 3; ++i) {
            const float* rp = &rs[(row + i) * VROW + cb];
            const float* vb = &vpool[cur * VSTR + (row + i) * VROW + cb];
            #pragma unroll
            for (int j = 0; j < 10; ++j) { rwin[i][j] = rp[j]; vwin[i][j] = vb[j]; }
        }
        float qv[8][10];
        #pragma unroll
        for (int a = 0; a < 10; ++a) {
            #pragma unroll
            for (int p = 0; p < 8; ++p) {
                float acc = 0.f;
                #pragma unroll
                for (int d = 0; d < 9; ++d) {
                    acc = fmaf(w_sw2[d * 20 + a],      rwin[d / 3][p + d % 3], acc);
                    acc = fmaf(w_sw2[d * 20 + 10 + a], vwin[d / 3][p + d % 3], acc);
                }
                qv[p][a] = acc;
            }
        }
        // store q: 80 contiguous floats (8 px x 10 actions), 16B-aligned
        {
            float4* qp4 = (float4*)(out + 2048 + ((size_t)((b * 64 + row) * 64 + cb)) * 10);
            #pragma unroll
            for (int g = 0; g < 20; ++g)
                qp4[g] = make_float4(qv[(g * 4) / 10][(g * 4) % 10],
                                     qv[(g * 4 + 1) / 10][(g * 4 + 1) % 10],
                                     qv[(g * 4 + 2) / 10][(g * 4 + 2) % 10],
                                     qv[(g * 4 + 3) / 10][(g * 4 + 3) % 10]);
        }
        if (row == s1) {
            #pragma unroll
            for (int p = 0; p < 8; ++p)
                if (s2 == cb + p) {
                    #pragma unroll
                    for (int a = 0; a < 10; ++a) qsel[a] = qv[p][a];
                }
        }
    }
    __syncthreads();

    // ---- dense + softmax (thread 0), q_out (threads 0..9) ----
    if (t == 0) {
        float logits[8];
        float m = -1e30f;
        #pragma unroll
        for (int j = 0; j < 8; ++j) {
            float s = 0.f;
            #pragma unroll
            for (int a = 0; a < 10; ++a) s += qsel[a] * w_dense[a * 8 + j];
            logits[j] = s;
            m = fmaxf(m, s);
        }
        float sum = 0.f;
        float e[8];
        #pragma unroll
        for (int j = 0; j < 8; ++j) { e[j] = expf(logits[j] - m); sum += e[j]; }
        float inv = 1.f / sum;
        #pragma unroll
        for (int j = 0; j < 8; ++j) {
            out[b * 8 + j] = logits[j];
            out[1024 + b * 8 + j] = e[j] * inv;
        }
    }
    if (t < 10) out[5244928 + b * 10 + t] = qsel[t];
}

extern "C" void kernel_launch(void* const* d_in, const int* in_sizes, int n_in,
                              void* d_out, int out_size, void* d_ws, size_t ws_size,
                              hipStream_t stream) {
    const float* x      = (const float*)d_in[0];
    const int*   S1     = (const int*)d_in[1];
    const int*   S2     = (const int*)d_in[2];
    const int*   VInum  = (const int*)d_in[3];
    const float* w0     = (const float*)d_in[4];
    const float* b0     = (const float*)d_in[5];
    const float* w_r    = (const float*)d_in[6];
    const float* w_q    = (const float*)d_in[7];
    const float* w_sw   = (const float*)d_in[8];
    const float* w_sw2  = (const float*)d_in[9];
    const float* w_dense= (const float*)d_in[10];
    float* out = (float*)d_out;

    vin_kernel<<<128, 512, 0, stream>>>(x, S1, S2, VInum, w0, b0, w_r, w_q,
                                        w_sw, w_sw2, w_dense, out);
}

// Round 11
// 197.616 us; speedup vs baseline: 2.8089x; 1.0128x over previous
//
#include <hip/hip_runtime.h>
#include <math.h>

// VIN forward on MI355X — single fused kernel (128 WGs x 512 thr, 8 px/thread).
// Sizes: N=128, H=W=64, CH_I=2, CH_H=150, CH_Q=10, N_ACT=8, VInum=36.
//
// R10 -> R11 change (K-loop only; prologue is R10's class-stencil form):
//  R10 reframe: active-CU VALUBusy ~77% -> K-loop is VALU+LDS co-bound, not
//  latency-bound. R6 proved v_pk_fma_f32 is full-rate (VALU busy halved);
//  R9 proved clustered wide LDS loads regress vs sprinkled scalars. R6
//  combined pk WITH clustering (9 hoisted b64/ap) — the untested cell is
//  pk + SPRINKLED loads: one ds_read_b64 per 8 pk-FMAs (same load-use
//  density as the proven R5/R10 stream). VALU/iter ~halves, LDS instrs
//  128 -> 83. Paired max is exactly associative -> bit-identical output.

typedef float v2f __attribute__((ext_vector_type(2)));

static __device__ __forceinline__ v2f splat2(float s) { v2f r; r.x = s; r.y = s; return r; }
static __device__ __forceinline__ v2f pkfma(v2f w, float v, v2f a) {
#if __has_builtin(__builtin_elementwise_fma)
    return __builtin_elementwise_fma(w, splat2(v), a);
#else
    v2f r; r.x = fmaf(w.x, v, a.x); r.y = fmaf(w.y, v, a.y); return r;
#endif
}
static __device__ __forceinline__ v2f pkmax(v2f a, v2f b) {
#if __has_builtin(__builtin_elementwise_max)
    return __builtin_elementwise_max(a, b);
#else
    v2f r; r.x = fmaxf(a.x, b.x); r.y = fmaxf(a.y, b.y); return r;
#endif
}

#define XROW 69
#define VROW 67
#define VSTR (66 * VROW)          // 4422 floats per v buffer

__global__ void
__attribute__((amdgpu_flat_work_group_size(512, 512)))
__attribute__((amdgpu_waves_per_eu(2, 2)))
vin_kernel(const float* __restrict__ x,
           const int* __restrict__ S1,
           const int* __restrict__ S2,
           const int* __restrict__ VInum,
           const float* __restrict__ w0,
           const float* __restrict__ b0,
           const float* __restrict__ w_r,
           const float* __restrict__ w_q,
           const float* __restrict__ w_sw,
           const float* __restrict__ w_sw2,
           const float* __restrict__ w_dense,
           float* __restrict__ out) {
    const int b = blockIdx.x;
    const int t = threadIdx.x;

    __shared__ float xs0[68 * XROW];     // x ch0, [y+2][x+2], 2-halo of zeros
    __shared__ float xs1[68 * XROW];     // x ch1
    __shared__ float rs[66 * VROW];      // r with 1-halo of zeros
    __shared__ float vpool[2 * VSTR];    // v double buffer, 1-halo of zeros
    __shared__ float wtA[1620];          // P chunk partials: 162 entries x 10
    __shared__ float Pp[450];            // P[d][e5x5][ci], zero-init (162 filled)
    __shared__ float Bt[90];             // bias chunk partials: 9 d x 10
    __shared__ float Bv[9];              // B[d] = w_r[d].b0
    __shared__ float W5c[459];           // 9 classes x (50 weights + bias)
    __shared__ v2f   swv2[45];           // w_sw v-part action-pairs: [d][ap]
    __shared__ float qsel[10];

    // ---- zero LDS (halos must be 0; Pp must be 0 for invalid combos) ----
    for (int i = t; i < 68 * XROW; i += 512) { xs0[i] = 0.f; xs1[i] = 0.f; }
    for (int i = t; i < 66 * VROW; i += 512) rs[i] = 0.f;
    for (int i = t; i < 2 * VSTR; i += 512) vpool[i] = 0.f;
    if (t < 450) Pp[t] = 0.f;
    if (t < 45) {
        int d = t / 5, ap = t - d * 5;
        v2f w; w.x = w_sw[d * 20 + 10 + 2 * ap]; w.y = w_sw[d * 20 + 10 + 2 * ap + 1];
        swv2[t] = w;
    }
    __syncthreads();

    const int row = t >> 3;          // 0..63
    const int cb  = (t & 7) << 3;    // 0,8,...,56  (8 px per thread)

    // ---- stage x into split planes (16 contiguous floats = 4x float4) ----
    {
        const float* xb = x + (size_t)b * 64 * 64 * 2;
        const float4* xp = (const float4*)(xb + (row * 64 + cb) * 2);
        #pragma unroll
        for (int g = 0; g < 4; ++g) {
            float4 v4 = xp[g];
            int px = cb + g * 2;
            xs0[(row + 2) * XROW + px + 2] = v4.x;
            xs1[(row + 2) * XROW + px + 2] = v4.y;
            xs0[(row + 2) * XROW + px + 3] = v4.z;
            xs1[(row + 2) * XROW + px + 3] = v4.w;
        }
    }
    // ---- round A: P chunk partials (1620 items) + bias chunks (90) ----
    for (int idx = t; idx < 1620; idx += 512) {
        int entry = idx / 10, ch = idx - entry * 10;
        int d = entry / 18, rem = entry % 18;
        int uu = rem >> 1, ci = rem & 1;
        int c0 = ch * 15;
        const float* wr = w_r + d * 150;
        const float* wp = w0 + (uu * 2 + ci) * 150;
        float s = 0.f;
        for (int c = c0; c < c0 + 15; ++c) s += wr[c] * wp[c];
        wtA[idx] = s;
    }
    if (t < 90) {
        int d = t / 10, ch = t - d * 10, c0 = ch * 15;
        float s = 0.f;
        for (int c = c0; c < c0 + 15; ++c) s += w_r[d * 150 + c] * b0[c];
        Bt[t] = s;
    }
    __syncthreads();
    // ---- round B: reduce P entries (162) and B (9) ----
    if (t < 162) {
        float s = 0.f;
        #pragma unroll
        for (int i = 0; i < 10; ++i) s += wtA[t * 10 + i];
        int d = t / 18, rem = t % 18;
        int uu = rem >> 1, ci = rem & 1;
        int dy = d / 3 - 1, dx = d % 3 - 1;
        int uy = uu / 3 - 1, ux = uu % 3 - 1;
        int eidx = (dy + uy + 2) * 5 + (dx + ux + 2);
        Pp[d * 50 + eidx * 2 + ci] = s;
    } else if (t >= 256 && t < 265) {
        int d = t - 256;
        float s = 0.f;
        #pragma unroll
        for (int i = 0; i < 10; ++i) s += Bt[d * 10 + i];
        Bv[d] = s;
    }
    __syncthreads();
    // ---- round C: class subset-sums W5c[9][51] ----
    if (t < 459) {
        int cls = t / 51, j = t - cls * 51;
        int cy = cls / 3, cx = cls % 3;
        float s = 0.f;
        #pragma unroll
        for (int d = 0; d < 9; ++d) {
            int dy = d / 3 - 1, dx = d % 3 - 1;
            bool ok = (cy == 0 || (cy == 1 ? dy >= 0 : dy <= 0)) &&
                      (cx == 0 || (cx == 1 ? dx >= 0 : dx <= 0));
            if (ok) s += (j < 50) ? Pp[d * 50 + j] : Bv[d];
        }
        W5c[t] = s;
    }
    __syncthreads();

    // ---- r everywhere via class-weighted 5x5 stencil ----
    {
        int cy = (row == 0) ? 1 : (row == 63) ? 2 : 0;
        #pragma unroll
        for (int p = 0; p < 8; ++p) {
            int xx = cb + p;
            int cx = (xx == 0) ? 1 : (xx == 63) ? 2 : 0;
            const float* Wp = &W5c[(cy * 3 + cx) * 51];
            float acc = Wp[50];
            #pragma unroll
            for (int e = 0; e < 25; ++e) {
                int xi = (row + e / 5) * XROW + (xx + e % 5);
                acc = fmaf(xs0[xi], Wp[e * 2], acc);
                acc = fmaf(xs1[xi], Wp[e * 2 + 1], acc);
            }
            rs[(row + 1) * VROW + (xx + 1)] = acc;
        }
    }
    __syncthreads();

    const int K = VInum[0];

    // ---- Rsw precompute (packed action-pairs) + first step (w_q) ----
    v2f Rsw2[8][5];
    {
        float rwin[3][10];
        #pragma unroll
        for (int i = 0; i < 3; ++i) {
            const float* rp = &rs[(row + i) * VROW + cb];
            #pragma unroll
            for (int j = 0; j < 10; ++j) rwin[i][j] = rp[j];
        }
        float vmax[8];
        #pragma unroll
        for (int a = 0; a < 10; ++a) {
            #pragma unroll
            for (int p = 0; p < 8; ++p) {
                float accR = 0.f, accQ = 0.f;
                #pragma unroll
                for (int d = 0; d < 9; ++d) {
                    float rv = rwin[d / 3][p + d % 3];
                    accR = fmaf(w_sw[d * 20 + a], rv, accR);
                    accQ = fmaf(w_q[d * 20 + a],  rv, accQ);
                }
                if (a & 1) Rsw2[p][a >> 1].y = accR; else Rsw2[p][a >> 1].x = accR;
                vmax[p] = (a == 0) ? accQ : fmaxf(vmax[p], accQ);
            }
        }
        #pragma unroll
        for (int p = 0; p < 8; ++p)
            vpool[0 * VSTR + (row + 1) * VROW + (cb + p + 1)] = vmax[p];
    }
    __syncthreads();

    // ---- K-1 shared-weight VI steps: pk math, SPRINKLED b64 weight reads ----
    int cur = 0;
    for (int it = 0; it < K - 1; ++it) {
        const float* vb = &vpool[cur * VSTR + row * VROW + cb];
        float vwin[3][10];
        #pragma unroll
        for (int i = 0; i < 3; ++i)
            #pragma unroll
            for (int j = 0; j < 10; ++j) vwin[i][j] = vb[i * VROW + j];
        int nxt = cur ^ 1;
        v2f vmax2[8];
        #pragma unroll
        for (int ap = 0; ap < 5; ++ap) {
            v2f acc2[8];
            #pragma unroll
            for (int d = 0; d < 9; ++d) {
                v2f w2 = swv2[d * 5 + ap];   // one b64 read per 8 pk-FMAs
                #pragma unroll
                for (int p = 0; p < 8; ++p) {
                    float vv = vwin[d / 3][p + d % 3];
                    acc2[p] = (d == 0) ? pkfma(w2, vv, Rsw2[p][ap])
                                       : pkfma(w2, vv, acc2[p]);
                }
            }
            #pragma unroll
            for (int p = 0; p < 8; ++p)
                vmax2[p] = (ap == 0) ? acc2[p] : pkmax(vmax2[p], acc2[p]);
        }
        #pragma unroll
        for (int p = 0; p < 8; ++p)
            vpool[nxt * VSTR + (row + 1) * VROW + (cb + p + 1)] =
                fmaxf(vmax2[p].x, vmax2[p].y);
        cur = nxt;
        __syncthreads();
    }

    // ---- final step with w_sw2: q -> global, gather (S1,S2) ----
    const int s1 = S1[b], s2 = S2[b];
    {
        float rwin[3][10], vwin[3][10];
        #pragma unroll
        for (int i = 0; i < 3; ++i) {
            const float* rp = &rs[(row + i) * VROW + cb];
            const float* vb = &vpool[cur * VSTR + (row + i) * VROW + cb];
            #pragma unroll
            for (int j = 0; j < 10; ++j) { rwin[i][j] = rp[j]; vwin[i][j] = vb[j]; }
        }
        float qv[8][10];
        #pragma unroll
        for (int a = 0; a < 10; ++a) {
            #pragma unroll
            for (int p = 0; p < 8; ++p) {
                float acc = 0.f;
                #pragma unroll
                for (int d = 0; d < 9; ++d) {
                    acc = fmaf(w_sw2[d * 20 + a],      rwin[d / 3][p + d % 3], acc);
                    acc = fmaf(w_sw2[d * 20 + 10 + a], vwin[d / 3][p + d % 3], acc);
                }
                qv[p][a] = acc;
            }
        }
        // store q: 80 contiguous floats (8 px x 10 actions), 16B-aligned
        {
            float4* qp4 = (float4*)(out + 2048 + ((size_t)((b * 64 + row) * 64 + cb)) * 10);
            #pragma unroll
            for (int g = 0; g < 20; ++g)
                qp4[g] = make_float4(qv[(g * 4) / 10][(g * 4) % 10],
                                     qv[(g * 4 + 1) / 10][(g * 4 + 1) % 10],
                                     qv[(g * 4 + 2) / 10][(g * 4 + 2) % 10],
                                     qv[(g * 4 + 3) / 10][(g * 4 + 3) % 10]);
        }
        if (row == s1) {
            #pragma unroll
            for (int p = 0; p < 8; ++p)
                if (s2 == cb + p) {
                    #pragma unroll
                    for (int a = 0; a < 10; ++a) qsel[a] = qv[p][a];
                }
        }
    }
    __syncthreads();

    // ---- dense + softmax (thread 0), q_out (threads 0..9) ----
    if (t == 0) {
        float logits[8];
        float m = -1e30f;
        #pragma unroll
        for (int j = 0; j < 8; ++j) {
            float s = 0.f;
            #pragma unroll
            for (int a = 0; a < 10; ++a) s += qsel[a] * w_dense[a * 8 + j];
            logits[j] = s;
            m = fmaxf(m, s);
        }
        float sum = 0.f;
        float e[8];
        #pragma unroll
        for (int j = 0; j < 8; ++j) { e[j] = expf(logits[j] - m); sum += e[j]; }
        float inv = 1.f / sum;
        #pragma unroll
        for (int j = 0; j < 8; ++j) {
            out[b * 8 + j] = logits[j];
            out[1024 + b * 8 + j] = e[j] * inv;
        }
    }
    if (t < 10) out[5244928 + b * 10 + t] = qsel[t];
}

extern "C" void kernel_launch(void* const* d_in, const int* in_sizes, int n_in,
                              void* d_out, int out_size, void* d_ws, size_t ws_size,
                              hipStream_t stream) {
    const float* x      = (const float*)d_in[0];
    const int*   S1     = (const int*)d_in[1];
    const int*   S2     = (const int*)d_in[2];
    const int*   VInum  = (const int*)d_in[3];
    const float* w0     = (const float*)d_in[4];
    const float* b0     = (const float*)d_in[5];
    const float* w_r    = (const float*)d_in[6];
    const float* w_q    = (const float*)d_in[7];
    const float* w_sw   = (const float*)d_in[8];
    const float* w_sw2  = (const float*)d_in[9];
    const float* w_dense= (const float*)d_in[10];
    float* out = (float*)d_out;

    vin_kernel<<<128, 512, 0, stream>>>(x, S1, S2, VInum, w0, b0, w_r, w_q,
                                        w_sw, w_sw2, w_dense, out);
}